// Round 5
// baseline (1071.131 us; speedup 1.0000x reference)
//
#include <hip/hip_runtime.h>
#include <math.h>

#define N_NODES 100000
#define S1 50
#define S2 10
#define HID 128
#define NT 32   // nodes per block in enc2_mlp (512 threads)

// ---------------- kernel 1: agg1d[n] = (sum_{j in neigh1[n]} feat[j] + feat[n]) / 51  (fp64)
__global__ __launch_bounds__(256) void agg1_kernel(
    const float* __restrict__ feat, const int* __restrict__ neigh1,
    double* __restrict__ agg1d)
{
    const int wid  = threadIdx.x >> 6;
    const int lane = threadIdx.x & 63;
    const int n = blockIdx.x * 4 + wid;
    if (n >= N_NODES) return;

    double f0 = 0.0, f1 = 0.0, f2 = 0.0;
    if (lane < S1) {
        int j = neigh1[n * S1 + lane];
        f0 = (double)feat[j * 3 + 0];
        f1 = (double)feat[j * 3 + 1];
        f2 = (double)feat[j * 3 + 2];
    } else if (lane == S1) {
        f0 = (double)feat[n * 3 + 0];
        f1 = (double)feat[n * 3 + 1];
        f2 = (double)feat[n * 3 + 2];
    }
    #pragma unroll
    for (int off = 32; off > 0; off >>= 1) {
        f0 += __shfl_down(f0, off);
        f1 += __shfl_down(f1, off);
        f2 += __shfl_down(f2, off);
    }
    if (lane == 0) {
        agg1d[n * 3 + 0] = f0 / 51.0;
        agg1d[n * 3 + 1] = f1 / 51.0;
        agg1d[n * 3 + 2] = f2 / 51.0;
    }
}

// ---------------- kernel 2: enc2 + MLP + score, fp64. 512 threads, 32 nodes/block.
// 64-k weight chunks (2 per phase), register-prefetched staging (global->reg->LDS),
// so chunk c+1's loads overlap chunk c's compute. 1 block/CU (106.8 KB LDS).
__global__ __launch_bounds__(512) void enc2_mlp_kernel(
    const int* __restrict__ nodes, const int* __restrict__ neigh2,
    const double* __restrict__ agg1d,
    const float* __restrict__ W1, const float* __restrict__ W2,
    const float* __restrict__ w_a, const float* __restrict__ b_a,
    const float* __restrict__ w_b, const float* __restrict__ b_b,
    const float* __restrict__ w_c, const float* __restrict__ b_c,
    const int* __restrict__ psz, const int* __restrict__ npe,
    double* __restrict__ scoresd)
{
    __shared__ float  sW[128 * 66];          // 33.8 KB: one 64-k weight chunk (fp32)
    __shared__ double sA[NT * 128];          // 32 KB
    __shared__ double sB[NT * 128];          // 32 KB
    __shared__ float  sW1[128 * 3];          // 1.5 KB
    __shared__ double sG[NT * (S2 + 1) * 3]; // 8.25 KB

    const int tid  = threadIdx.x;
    const int base = blockIdx.x * NT;        // 3125*32 == 100000, no guards

    // ---- phase 0: stage W1 + gathered agg1 rows (480 items, 512 threads)
    if (tid < 128) {
        sW1[tid * 3 + 0] = W1[tid * 3 + 0];
        sW1[tid * 3 + 1] = W1[tid * 3 + 1];
        sW1[tid * 3 + 2] = W1[tid * 3 + 2];
    } else if (tid < 128 + NT * (S2 + 1)) {
        int t  = tid - 128;
        int ns = t / 11, j = t - ns * 11;
        int node = nodes[base + ns];
        int src  = (j == 0) ? node : neigh2[node * S2 + (j - 1)];
        sG[t * 3 + 0] = agg1d[src * 3 + 0];
        sG[t * 3 + 1] = agg1d[src * 3 + 1];
        sG[t * 3 + 2] = agg1d[src * 3 + 2];
    }
    __syncthreads();

    // ---- phase 1: agg2[ns][t] = mean_j relu(W1[t].row_j) -> sA
    {
        const int t = tid & 127;             // invariant across strided iters (512%128==0)
        const double wx = (double)sW1[t * 3 + 0];
        const double wy = (double)sW1[t * 3 + 1];
        const double wz = (double)sW1[t * 3 + 2];
        #pragma unroll
        for (int s = 0; s < NT * 128 / 512; s++) {
            int idx = tid + s * 512;
            int ns = idx >> 7;
            double acc = 0.0;
            #pragma unroll
            for (int j = 0; j <= S2; j++) {
                const double* a = &sG[(ns * 11 + j) * 3];
                acc += fmax(wx * a[0] + wy * a[1] + wz * a[2], 0.0);
            }
            sA[idx] = acc / 11.0;
        }
    }
    // no barrier: phase-2's first sW write + barrier covers sA visibility

    const int tq = tid & 63;   // outs {tq, tq+64}
    const int nq = tid >> 6;   // wave id 0..7 -> nodes {4nq .. 4nq+3}

    // ---- phase 2: emb = relu(W2 @ agg2) : sA -> sB
    {
        double acc0[4] = {0,0,0,0}, acc1[4] = {0,0,0,0};
        float2 wreg[8];
        #pragma unroll
        for (int i = 0; i < 8; i++) {        // prefetch chunk 0
            int idx = tid + i * 512;         // 0..4095
            int t = idx >> 5, kp = idx & 31;
            wreg[i] = *(const float2*)&W2[t * 128 + 2 * kp];
        }
        for (int c = 0; c < 2; c++) {
            #pragma unroll
            for (int i = 0; i < 8; i++) {
                int idx = tid + i * 512;
                int t = idx >> 5, kp = idx & 31;
                *(float2*)&sW[t * 66 + 2 * kp] = wreg[i];
            }
            __syncthreads();
            if (c == 0) {
                #pragma unroll
                for (int i = 0; i < 8; i++) {   // prefetch chunk 1 (overlaps compute)
                    int idx = tid + i * 512;
                    int t = idx >> 5, kp = idx & 31;
                    wreg[i] = *(const float2*)&W2[t * 128 + 64 + 2 * kp];
                }
            }
            #pragma unroll
            for (int kp = 0; kp < 32; kp++) {
                float2 w0 = *(const float2*)&sW[tq * 66 + 2 * kp];
                float2 w1 = *(const float2*)&sW[(tq + 64) * 66 + 2 * kp];
                double w0x = (double)w0.x, w0y = (double)w0.y;
                double w1x = (double)w1.x, w1y = (double)w1.y;
                #pragma unroll
                for (int n = 0; n < 4; n++) {
                    double2 a = *(const double2*)&sA[(nq * 4 + n) * 128 + c * 64 + 2 * kp];
                    acc0[n] += w0x * a.x + w0y * a.y;
                    acc1[n] += w1x * a.x + w1y * a.y;
                }
            }
            __syncthreads();
        }
        #pragma unroll
        for (int n = 0; n < 4; n++) {
            sB[(nq * 4 + n) * 128 + tq]      = fmax(acc0[n], 0.0);
            sB[(nq * 4 + n) * 128 + tq + 64] = fmax(acc1[n], 0.0);
        }
    }

    // ---- phase 3: xa = relu(w_a[:,:128] @ emb + w_a[:,128]*rem + b_a) : sB -> sA
    {
        double acc0[4] = {0,0,0,0}, acc1[4] = {0,0,0,0};
        float wreg[16];
        #pragma unroll
        for (int i = 0; i < 16; i++) {       // prefetch chunk 0 (stride 129: b32)
            int idx = tid + i * 512;         // 0..8191
            int o = idx >> 6, k = idx & 63;
            wreg[i] = w_a[o * 129 + k];
        }
        for (int c = 0; c < 2; c++) {
            #pragma unroll
            for (int i = 0; i < 16; i++) {
                int idx = tid + i * 512;
                int o = idx >> 6, k = idx & 63;
                sW[o * 66 + k] = wreg[i];
            }
            __syncthreads();
            if (c == 0) {
                #pragma unroll
                for (int i = 0; i < 16; i++) {
                    int idx = tid + i * 512;
                    int o = idx >> 6, k = idx & 63;
                    wreg[i] = w_a[o * 129 + 64 + k];
                }
            }
            #pragma unroll
            for (int kp = 0; kp < 32; kp++) {
                float2 w0 = *(const float2*)&sW[tq * 66 + 2 * kp];
                float2 w1 = *(const float2*)&sW[(tq + 64) * 66 + 2 * kp];
                double w0x = (double)w0.x, w0y = (double)w0.y;
                double w1x = (double)w1.x, w1y = (double)w1.y;
                #pragma unroll
                for (int n = 0; n < 4; n++) {
                    double2 a = *(const double2*)&sB[(nq * 4 + n) * 128 + c * 64 + 2 * kp];
                    acc0[n] += w0x * a.x + w0y * a.y;
                    acc1[n] += w1x * a.x + w1y * a.y;
                }
            }
            __syncthreads();
        }
        const double rem = (double)(psz[0] - npe[0]);
        double add0 = (double)w_a[tq * 129 + 128] * rem + (double)b_a[tq];
        double add1 = (double)w_a[(tq + 64) * 129 + 128] * rem + (double)b_a[tq + 64];
        #pragma unroll
        for (int n = 0; n < 4; n++) {
            sA[(nq * 4 + n) * 128 + tq]      = fmax(acc0[n] + add0, 0.0);
            sA[(nq * 4 + n) * 128 + tq + 64] = fmax(acc1[n] + add1, 0.0);
        }
    }

    // ---- phase 4: xb = relu(w_b @ xa + b_b) : sA -> sB[ns*64 + o], o<64
    {
        const int tq4 = tid & 31;   // outs {tq4, tq4+32}
        const int ng  = tid >> 5;   // 0..15 -> nodes {2ng, 2ng+1}
        double acc00 = 0, acc01 = 0, acc10 = 0, acc11 = 0;
        float2 wreg[4];
        #pragma unroll
        for (int i = 0; i < 4; i++) {        // prefetch chunk 0
            int idx = tid + i * 512;         // 0..2047
            int o = idx >> 5, kp = idx & 31;
            wreg[i] = *(const float2*)&w_b[o * 128 + 2 * kp];
        }
        for (int c = 0; c < 2; c++) {
            #pragma unroll
            for (int i = 0; i < 4; i++) {
                int idx = tid + i * 512;
                int o = idx >> 5, kp = idx & 31;
                *(float2*)&sW[o * 66 + 2 * kp] = wreg[i];
            }
            __syncthreads();
            if (c == 0) {
                #pragma unroll
                for (int i = 0; i < 4; i++) {
                    int idx = tid + i * 512;
                    int o = idx >> 5, kp = idx & 31;
                    wreg[i] = *(const float2*)&w_b[o * 128 + 64 + 2 * kp];
                }
            }
            #pragma unroll
            for (int kp = 0; kp < 32; kp++) {
                float2 w0 = *(const float2*)&sW[tq4 * 66 + 2 * kp];
                float2 w1 = *(const float2*)&sW[(tq4 + 32) * 66 + 2 * kp];
                double w0x = (double)w0.x, w0y = (double)w0.y;
                double w1x = (double)w1.x, w1y = (double)w1.y;
                double2 a0 = *(const double2*)&sA[(2 * ng) * 128 + c * 64 + 2 * kp];
                double2 a1 = *(const double2*)&sA[(2 * ng + 1) * 128 + c * 64 + 2 * kp];
                acc00 += w0x * a0.x + w0y * a0.y;
                acc01 += w0x * a1.x + w0y * a1.y;
                acc10 += w1x * a0.x + w1y * a0.y;
                acc11 += w1x * a1.x + w1y * a1.y;
            }
            __syncthreads();
        }
        double bb0 = (double)b_b[tq4], bb1 = (double)b_b[tq4 + 32];
        sB[(2 * ng) * 64 + tq4]          = fmax(acc00 + bb0, 0.0);
        sB[(2 * ng + 1) * 64 + tq4]      = fmax(acc01 + bb0, 0.0);
        sB[(2 * ng) * 64 + tq4 + 32]     = fmax(acc10 + bb1, 0.0);
        sB[(2 * ng + 1) * 64 + tq4 + 32] = fmax(acc11 + bb1, 0.0);
    }
    __syncthreads();

    // ---- phase 5: score = w_c . xb + b_c   (16 threads per node, 32 nodes)
    {
        const int j = tid & 15, ns = tid >> 4;
        double v = 0.0;
        #pragma unroll
        for (int r = 0; r < 4; r++)
            v += (double)w_c[j + 16 * r] * sB[ns * 64 + j + 16 * r];
        v += __shfl_down(v, 8);
        v += __shfl_down(v, 4);
        v += __shfl_down(v, 2);
        v += __shfl_down(v, 1);
        if (j == 0)
            scoresd[base + ns] = v + (double)b_c[0];
    }
}

// ---------------- softmax chain: 3 kernels ----------------
__global__ __launch_bounds__(256) void reduce_max_kernel(
    const double* __restrict__ s, double* __restrict__ pmax)
{
    __shared__ double red[4];
    const int tid = threadIdx.x;
    double m = -INFINITY;
    for (int i = blockIdx.x * 256 + tid; i < N_NODES; i += gridDim.x * 256)
        m = fmax(m, s[i]);
    #pragma unroll
    for (int off = 32; off > 0; off >>= 1) m = fmax(m, __shfl_down(m, off));
    if ((tid & 63) == 0) red[tid >> 6] = m;
    __syncthreads();
    if (tid == 0)
        pmax[blockIdx.x] = fmax(fmax(red[0], red[1]), fmax(red[2], red[3]));
}

// each block re-reduces pmax[256] -> m, then exp + partial sum
__global__ __launch_bounds__(256) void exp_sum_kernel(
    double* __restrict__ s, const double* __restrict__ pmax,
    double* __restrict__ psum)
{
    __shared__ double red[4];
    const int tid = threadIdx.x;
    double m = pmax[tid];
    #pragma unroll
    for (int off = 32; off > 0; off >>= 1) m = fmax(m, __shfl_down(m, off));
    if ((tid & 63) == 0) red[tid >> 6] = m;
    __syncthreads();
    m = fmax(fmax(red[0], red[1]), fmax(red[2], red[3]));
    __syncthreads();

    double acc = 0.0;
    for (int i = blockIdx.x * 256 + tid; i < N_NODES; i += gridDim.x * 256) {
        double e = exp(s[i] - m);
        s[i] = e;
        acc += e;
    }
    #pragma unroll
    for (int off = 32; off > 0; off >>= 1) acc += __shfl_down(acc, off);
    if ((tid & 63) == 0) red[tid >> 6] = acc;
    __syncthreads();
    if (tid == 0)
        psum[blockIdx.x] = (red[0] + red[1]) + (red[2] + red[3]);
}

// each block re-reduces psum[256] -> S, then out = e / S (fp32 store)
__global__ __launch_bounds__(256) void scale_kernel(
    const double* __restrict__ e, const double* __restrict__ psum,
    float* __restrict__ out)
{
    __shared__ double red[4];
    const int tid = threadIdx.x;
    double acc = psum[tid];
    #pragma unroll
    for (int off = 32; off > 0; off >>= 1) acc += __shfl_down(acc, off);
    if ((tid & 63) == 0) red[tid >> 6] = acc;
    __syncthreads();
    const double invS = 1.0 / ((red[0] + red[1]) + (red[2] + red[3]));
    const int i = blockIdx.x * 256 + tid;
    if (i < N_NODES) out[i] = (float)(e[i] * invS);
}

// ---------------- launch ----------------
extern "C" void kernel_launch(void* const* d_in, const int* in_sizes, int n_in,
                              void* d_out, int out_size, void* d_ws, size_t ws_size,
                              hipStream_t stream)
{
    const int*   nodes = (const int*)  d_in[0];
    const float* feat  = (const float*)d_in[1];
    const int*   n1    = (const int*)  d_in[2];
    const int*   n2    = (const int*)  d_in[3];
    const float* W1    = (const float*)d_in[4];
    const float* W2    = (const float*)d_in[5];
    const float* w_a   = (const float*)d_in[6];
    const float* b_a   = (const float*)d_in[7];
    const float* w_b   = (const float*)d_in[8];
    const float* b_b   = (const float*)d_in[9];
    const float* w_c   = (const float*)d_in[10];
    const float* b_c   = (const float*)d_in[11];
    const int*   psz   = (const int*)  d_in[12];
    const int*   npe   = (const int*)  d_in[13];
    float* out = (float*)d_out;

    double* agg1d   = (double*)d_ws;
    double* scoresd = agg1d + (size_t)N_NODES * 3;
    double* pmax    = scoresd + N_NODES;   // 256
    double* psum    = pmax + 256;          // 256

    agg1_kernel<<<(N_NODES + 3) / 4, 256, 0, stream>>>(feat, n1, agg1d);
    enc2_mlp_kernel<<<N_NODES / NT, 512, 0, stream>>>(
        nodes, n2, agg1d, W1, W2, w_a, b_a, w_b, b_b, w_c, b_c, psz, npe, scoresd);
    reduce_max_kernel<<<256, 256, 0, stream>>>(scoresd, pmax);
    exp_sum_kernel<<<256, 256, 0, stream>>>(scoresd, pmax, psum);
    scale_kernel<<<(N_NODES + 255) / 256, 256, 0, stream>>>(scoresd, psum, out);
}

// Round 7
// 588.982 us; speedup vs baseline: 1.8186x; 1.8186x over previous
//
#include <hip/hip_runtime.h>
#include <math.h>

#define N_NODES 100000
#define S1 50
#define S2 10
#define HID 128
#define NT 16   // nodes per block in enc2_mlp

// ---------------- kernel 1: agg1d[n] = (sum_{j in neigh1[n]} feat[j] + feat[n]) / 51  (fp64)
__global__ __launch_bounds__(256) void agg1_kernel(
    const float* __restrict__ feat, const int* __restrict__ neigh1,
    double* __restrict__ agg1d)
{
    const int wid  = threadIdx.x >> 6;
    const int lane = threadIdx.x & 63;
    const int n = blockIdx.x * 4 + wid;
    if (n >= N_NODES) return;

    double f0 = 0.0, f1 = 0.0, f2 = 0.0;
    if (lane < S1) {
        int j = neigh1[n * S1 + lane];
        f0 = (double)feat[j * 3 + 0];
        f1 = (double)feat[j * 3 + 1];
        f2 = (double)feat[j * 3 + 2];
    } else if (lane == S1) {
        f0 = (double)feat[n * 3 + 0];
        f1 = (double)feat[n * 3 + 1];
        f2 = (double)feat[n * 3 + 2];
    }
    #pragma unroll
    for (int off = 32; off > 0; off >>= 1) {
        f0 += __shfl_down(f0, off);
        f1 += __shfl_down(f1, off);
        f2 += __shfl_down(f2, off);
    }
    if (lane == 0) {
        agg1d[n * 3 + 0] = f0 / 51.0;
        agg1d[n * 3 + 1] = f1 / 51.0;
        agg1d[n * 3 + 2] = f2 / 51.0;
    }
}

// ---------------- kernel 2: enc2 + MLP + score, fp64 vector (proven arithmetic path).
// 128 threads = 2 waves, 16 nodes/block. Register blocking (No=4 outs x Nn=4 nodes)
// per thread: per k-pair 4 weight-b64 + 4 act-b128 LDS reads feed 16 fp64 FMAs
// (r4 was 2x4 -> 64 LDS cyc/16 FMA; this is ~80/32 per 2 threads = 2x less LDS/FMA).
// LDS 49 KB -> 3 blocks/CU. sG overlaid on sB (dead until phase-2 epilogue).
__global__ __launch_bounds__(128) void enc2_mlp_kernel(
    const int* __restrict__ nodes, const int* __restrict__ neigh2,
    const double* __restrict__ agg1d,
    const float* __restrict__ W1, const float* __restrict__ W2,
    const float* __restrict__ w_a, const float* __restrict__ b_a,
    const float* __restrict__ w_b, const float* __restrict__ b_b,
    const float* __restrict__ w_c, const float* __restrict__ b_c,
    const int* __restrict__ psz, const int* __restrict__ npe,
    double* __restrict__ scoresd)
{
    __shared__ float  sW[128 * 34];     // 17408 B: one 32-k weight chunk (fp32, exact)
    __shared__ double sA[NT * 128];     // 16384 B
    __shared__ double sB[NT * 128];     // 16384 B; first 5632 B double as sG in phases 0-1
    double* sG = sB;                    // overlay: 176 rows x 4 doubles (3 used)

    const int tid  = threadIdx.x;
    const int base = blockIdx.x * NT;   // 6250*16 == 100000, no guards

    // ---- phase 0: gather 11 agg1 rows per node into sG (176 items)
    for (int t = tid; t < NT * (S2 + 1); t += 128) {
        int ns = t / 11, j = t - ns * 11;
        int node = nodes[base + ns];
        int src  = (j == 0) ? node : neigh2[node * S2 + (j - 1)];
        sG[t * 4 + 0] = agg1d[src * 3 + 0];
        sG[t * 4 + 1] = agg1d[src * 3 + 1];
        sG[t * 4 + 2] = agg1d[src * 3 + 2];
    }
    __syncthreads();

    // ---- phase 1: agg2[ns][t] = mean_j relu(W1[t].row_j) -> sA[ns*128+t]
    // One node per thread (ns = tid&15); its 33 doubles hoisted to registers.
    {
        const int ns = tid & 15;
        double g0[11], g1[11], g2[11];
        #pragma unroll
        for (int j = 0; j < 11; j++) {
            g0[j] = sG[(ns * 11 + j) * 4 + 0];
            g1[j] = sG[(ns * 11 + j) * 4 + 1];
            g2[j] = sG[(ns * 11 + j) * 4 + 2];
        }
        #pragma unroll
        for (int s = 0; s < 16; s++) {
            int t = (tid >> 4) + 8 * s;               // t covers 0..127
            double wx = (double)W1[t * 3 + 0];        // 1.5 KB, L1-resident
            double wy = (double)W1[t * 3 + 1];
            double wz = (double)W1[t * 3 + 2];
            double acc = 0.0;
            #pragma unroll
            for (int j = 0; j < 11; j++)
                acc += fmax(wx * g0[j] + wy * g1[j] + wz * g2[j], 0.0);
            sA[ns * 128 + t] = acc / 11.0;
        }
    }
    // no barrier: phase-2 staging writes sW only, then barriers before sA reads;
    // sG(=sB) is read only above, first sB write is phase-2 epilogue (>=2 barriers later)

    const int tq = tid & 31;    // outs {tq, tq+32, tq+64, tq+96}
    const int ng = tid >> 5;    // nodes {4ng .. 4ng+3}

    // ---- phase 2: emb = relu(W2 @ agg2) : sA -> sB
    {
        double acc[4][4] = {};
        for (int c = 0; c < 4; c++) {
            for (int i = tid; i < 128 * 32; i += 128) {   // stage 32-k chunk
                int o = i >> 5, k = i & 31;
                sW[o * 34 + k] = W2[o * 128 + c * 32 + k];
            }
            __syncthreads();
            #pragma unroll 4
            for (int kp = 0; kp < 16; kp++) {
                double2 a[4];
                #pragma unroll
                for (int j = 0; j < 4; j++)
                    a[j] = *(const double2*)&sA[(4 * ng + j) * 128 + c * 32 + 2 * kp];
                #pragma unroll
                for (int i = 0; i < 4; i++) {
                    float2 wv = *(const float2*)&sW[(tq + 32 * i) * 34 + 2 * kp];
                    double wx = (double)wv.x, wy = (double)wv.y;
                    #pragma unroll
                    for (int j = 0; j < 4; j++)
                        acc[i][j] += wx * a[j].x + wy * a[j].y;
                }
            }
            __syncthreads();
        }
        #pragma unroll
        for (int i = 0; i < 4; i++)
            #pragma unroll
            for (int j = 0; j < 4; j++)
                sB[(4 * ng + j) * 128 + tq + 32 * i] = fmax(acc[i][j], 0.0);
    }

    // ---- phase 3: xa = relu(w_a[:,:128] @ emb + w_a[:,128]*rem + b_a) : sB -> sA
    {
        double acc[4][4] = {};
        for (int c = 0; c < 4; c++) {
            for (int i = tid; i < 128 * 32; i += 128) {   // stage (stride 129)
                int o = i >> 5, k = i & 31;
                sW[o * 34 + k] = w_a[o * 129 + c * 32 + k];
            }
            __syncthreads();
            #pragma unroll 4
            for (int kp = 0; kp < 16; kp++) {
                double2 a[4];
                #pragma unroll
                for (int j = 0; j < 4; j++)
                    a[j] = *(const double2*)&sB[(4 * ng + j) * 128 + c * 32 + 2 * kp];
                #pragma unroll
                for (int i = 0; i < 4; i++) {
                    float2 wv = *(const float2*)&sW[(tq + 32 * i) * 34 + 2 * kp];
                    double wx = (double)wv.x, wy = (double)wv.y;
                    #pragma unroll
                    for (int j = 0; j < 4; j++)
                        acc[i][j] += wx * a[j].x + wy * a[j].y;
                }
            }
            __syncthreads();
        }
        const double rem = (double)(psz[0] - npe[0]);
        #pragma unroll
        for (int i = 0; i < 4; i++) {
            int o = tq + 32 * i;
            double add = (double)w_a[o * 129 + 128] * rem + (double)b_a[o];
            #pragma unroll
            for (int j = 0; j < 4; j++)
                sA[(4 * ng + j) * 128 + o] = fmax(acc[i][j] + add, 0.0);
        }
    }

    // ---- phase 4: xb = relu(w_b @ xa + b_b) : sA -> sB[n*64+o], o<64
    {
        const int tq4 = tid & 15;   // outs {tq4, tq4+16, tq4+32, tq4+48}
        const int ng4 = tid >> 4;   // nodes {2ng4, 2ng4+1}
        double acc[4][2] = {};
        for (int c = 0; c < 4; c++) {
            for (int i = tid; i < 64 * 32; i += 128) {    // stage w_b chunk
                int o = i >> 5, k = i & 31;
                sW[o * 34 + k] = w_b[o * 128 + c * 32 + k];
            }
            __syncthreads();
            #pragma unroll 4
            for (int kp = 0; kp < 16; kp++) {
                double2 a[2];
                #pragma unroll
                for (int j = 0; j < 2; j++)
                    a[j] = *(const double2*)&sA[(2 * ng4 + j) * 128 + c * 32 + 2 * kp];
                #pragma unroll
                for (int i = 0; i < 4; i++) {
                    float2 wv = *(const float2*)&sW[(tq4 + 16 * i) * 34 + 2 * kp];
                    double wx = (double)wv.x, wy = (double)wv.y;
                    #pragma unroll
                    for (int j = 0; j < 2; j++)
                        acc[i][j] += wx * a[j].x + wy * a[j].y;
                }
            }
            __syncthreads();
        }
        #pragma unroll
        for (int i = 0; i < 4; i++) {
            int o = tq4 + 16 * i;
            double bb = (double)b_b[o];
            #pragma unroll
            for (int j = 0; j < 2; j++)
                sB[(2 * ng4 + j) * 64 + o] = fmax(acc[i][j] + bb, 0.0);
        }
    }
    __syncthreads();

    // ---- phase 5: score = w_c . xb + b_c   (8 threads per node)
    {
        const int j8 = tid & 7, ns = tid >> 3;
        double v = 0.0;
        #pragma unroll
        for (int r = 0; r < 8; r++)
            v += (double)w_c[j8 + 8 * r] * sB[ns * 64 + j8 + 8 * r];
        v += __shfl_down(v, 4);
        v += __shfl_down(v, 2);
        v += __shfl_down(v, 1);
        if (j8 == 0)
            scoresd[base + ns] = v + (double)b_c[0];
    }
}

// ---------------- softmax chain: 3 kernels (r5-proven) ----------------
__global__ __launch_bounds__(256) void reduce_max_kernel(
    const double* __restrict__ s, double* __restrict__ pmax)
{
    __shared__ double red[4];
    const int tid = threadIdx.x;
    double m = -INFINITY;
    for (int i = blockIdx.x * 256 + tid; i < N_NODES; i += gridDim.x * 256)
        m = fmax(m, s[i]);
    #pragma unroll
    for (int off = 32; off > 0; off >>= 1) m = fmax(m, __shfl_down(m, off));
    if ((tid & 63) == 0) red[tid >> 6] = m;
    __syncthreads();
    if (tid == 0)
        pmax[blockIdx.x] = fmax(fmax(red[0], red[1]), fmax(red[2], red[3]));
}

__global__ __launch_bounds__(256) void exp_sum_kernel(
    double* __restrict__ s, const double* __restrict__ pmax,
    double* __restrict__ psum)
{
    __shared__ double red[4];
    const int tid = threadIdx.x;
    double m = pmax[tid];
    #pragma unroll
    for (int off = 32; off > 0; off >>= 1) m = fmax(m, __shfl_down(m, off));
    if ((tid & 63) == 0) red[tid >> 6] = m;
    __syncthreads();
    m = fmax(fmax(red[0], red[1]), fmax(red[2], red[3]));
    __syncthreads();

    double acc = 0.0;
    for (int i = blockIdx.x * 256 + tid; i < N_NODES; i += gridDim.x * 256) {
        double e = exp(s[i] - m);
        s[i] = e;
        acc += e;
    }
    #pragma unroll
    for (int off = 32; off > 0; off >>= 1) acc += __shfl_down(acc, off);
    if ((tid & 63) == 0) red[tid >> 6] = acc;
    __syncthreads();
    if (tid == 0)
        psum[blockIdx.x] = (red[0] + red[1]) + (red[2] + red[3]);
}

__global__ __launch_bounds__(256) void scale_kernel(
    const double* __restrict__ e, const double* __restrict__ psum,
    float* __restrict__ out)
{
    __shared__ double red[4];
    const int tid = threadIdx.x;
    double acc = psum[tid];
    #pragma unroll
    for (int off = 32; off > 0; off >>= 1) acc += __shfl_down(acc, off);
    if ((tid & 63) == 0) red[tid >> 6] = acc;
    __syncthreads();
    const double invS = 1.0 / ((red[0] + red[1]) + (red[2] + red[3]));
    const int i = blockIdx.x * 256 + tid;
    if (i < N_NODES) out[i] = (float)(e[i] * invS);
}

// ---------------- launch ----------------
extern "C" void kernel_launch(void* const* d_in, const int* in_sizes, int n_in,
                              void* d_out, int out_size, void* d_ws, size_t ws_size,
                              hipStream_t stream)
{
    const int*   nodes = (const int*)  d_in[0];
    const float* feat  = (const float*)d_in[1];
    const int*   n1    = (const int*)  d_in[2];
    const int*   n2    = (const int*)  d_in[3];
    const float* W1    = (const float*)d_in[4];
    const float* W2    = (const float*)d_in[5];
    const float* w_a   = (const float*)d_in[6];
    const float* b_a   = (const float*)d_in[7];
    const float* w_b   = (const float*)d_in[8];
    const float* b_b   = (const float*)d_in[9];
    const float* w_c   = (const float*)d_in[10];
    const float* b_c   = (const float*)d_in[11];
    const int*   psz   = (const int*)  d_in[12];
    const int*   npe   = (const int*)  d_in[13];
    float* out = (float*)d_out;

    double* agg1d   = (double*)d_ws;
    double* scoresd = agg1d + (size_t)N_NODES * 3;
    double* pmax    = scoresd + N_NODES;   // 256
    double* psum    = pmax + 256;          // 256

    agg1_kernel<<<(N_NODES + 3) / 4, 256, 0, stream>>>(feat, n1, agg1d);
    enc2_mlp_kernel<<<N_NODES / NT, 128, 0, stream>>>(
        nodes, n2, agg1d, W1, W2, w_a, b_a, w_b, b_b, w_c, b_c, psz, npe, scoresd);
    reduce_max_kernel<<<256, 256, 0, stream>>>(scoresd, pmax);
    exp_sum_kernel<<<256, 256, 0, stream>>>(scoresd, pmax, psum);
    scale_kernel<<<(N_NODES + 255) / 256, 256, 0, stream>>>(scoresd, psum, out);
}

// Round 8
// 548.061 us; speedup vs baseline: 1.9544x; 1.0747x over previous
//
#include <hip/hip_runtime.h>
#include <math.h>

#define N_NODES 100000
#define S1 50
#define S2 10
#define HID 128
#define NT 16          // nodes per block in enc2_mlp
#define WSTRIDE 130    // padded w_a row stride (8B-aligned float2 rows)

// ---------------- kernel 1: agg1 (fp64) fused with w_a padding ----------------
__global__ __launch_bounds__(256) void prep_kernel(
    const float* __restrict__ feat, const int* __restrict__ neigh1,
    const float* __restrict__ w_a,
    double* __restrict__ agg1d, float* __restrict__ wpad)
{
    if (blockIdx.x >= 25000) {   // tail blocks: pad w_a 129 -> 130 stride
        int i = (blockIdx.x - 25000) * 256 + threadIdx.x;
        if (i < 128 * WSTRIDE) {
            int o = i / WSTRIDE, k = i - o * WSTRIDE;
            wpad[i] = (k < 129) ? w_a[o * 129 + k] : 0.f;
        }
        return;
    }
    const int wid  = threadIdx.x >> 6;
    const int lane = threadIdx.x & 63;
    const int n = blockIdx.x * 4 + wid;
    if (n >= N_NODES) return;

    double f0 = 0.0, f1 = 0.0, f2 = 0.0;
    if (lane < S1) {
        int j = neigh1[n * S1 + lane];
        f0 = (double)feat[j * 3 + 0];
        f1 = (double)feat[j * 3 + 1];
        f2 = (double)feat[j * 3 + 2];
    } else if (lane == S1) {
        f0 = (double)feat[n * 3 + 0];
        f1 = (double)feat[n * 3 + 1];
        f2 = (double)feat[n * 3 + 2];
    }
    #pragma unroll
    for (int off = 32; off > 0; off >>= 1) {
        f0 += __shfl_down(f0, off);
        f1 += __shfl_down(f1, off);
        f2 += __shfl_down(f2, off);
    }
    if (lane == 0) {
        agg1d[n * 3 + 0] = f0 / 51.0;
        agg1d[n * 3 + 1] = f1 / 51.0;
        agg1d[n * 3 + 2] = f2 / 51.0;
    }
}

// ---------------- kernel 2: enc2 + MLP + score, fp64 vector.
// 128 threads, 16 nodes/block. WEIGHTS READ DIRECTLY FROM GLOBAL (L2-resident,
// float2 with loop-invariant bases + immediate offsets) — LDS carries only
// activations (ping sA / pong sB, 32 KB -> 4 blocks/CU, 8 waves/CU).
// 5 barriers per block (was 26). Register blocking 4 outs x 4 nodes.
__global__ __launch_bounds__(128, 2) void enc2_mlp_kernel(
    const int* __restrict__ nodes, const int* __restrict__ neigh2,
    const double* __restrict__ agg1d,
    const float* __restrict__ W1, const float* __restrict__ W2,
    const float* __restrict__ wpad, const float* __restrict__ b_a,
    const float* __restrict__ w_b, const float* __restrict__ b_b,
    const float* __restrict__ w_c, const float* __restrict__ b_c,
    const int* __restrict__ psz, const int* __restrict__ npe,
    double* __restrict__ scoresd)
{
    __shared__ __align__(16) double sA[NT * HID];   // 16 KB
    __shared__ __align__(16) double sB[NT * HID];   // 16 KB; overlay sG in ph0-1
    double* sG = sB;                                // 176 rows x 4 doubles (3 used)

    const int tid  = threadIdx.x;
    const int base = blockIdx.x * NT;               // 6250*16 == 100000

    // ---- phase 0: gather 11 agg1 rows per node into sG
    for (int t = tid; t < NT * (S2 + 1); t += 128) {
        int ns = t / 11, j = t - ns * 11;
        int node = nodes[base + ns];
        int src  = (j == 0) ? node : neigh2[node * S2 + (j - 1)];
        sG[t * 4 + 0] = agg1d[src * 3 + 0];
        sG[t * 4 + 1] = agg1d[src * 3 + 1];
        sG[t * 4 + 2] = agg1d[src * 3 + 2];
    }
    __syncthreads();

    // ---- phase 1: agg2[ns][t] = mean_j relu(W1[t].row_j) -> sA[ns*128+t]
    {
        const int ns = tid & 15;
        double g0[11], g1[11], g2[11];
        #pragma unroll
        for (int j = 0; j < 11; j++) {
            g0[j] = sG[(ns * 11 + j) * 4 + 0];
            g1[j] = sG[(ns * 11 + j) * 4 + 1];
            g2[j] = sG[(ns * 11 + j) * 4 + 2];
        }
        #pragma unroll
        for (int s = 0; s < 16; s++) {
            int t = (tid >> 4) + 8 * s;
            double wx = (double)W1[t * 3 + 0];
            double wy = (double)W1[t * 3 + 1];
            double wz = (double)W1[t * 3 + 2];
            double acc = 0.0;
            #pragma unroll
            for (int j = 0; j < 11; j++)
                acc += fmax(wx * g0[j] + wy * g1[j] + wz * g2[j], 0.0);
            sA[ns * 128 + t] = acc / 11.0;
        }
    }
    __syncthreads();

    const int tq = tid & 31;    // outs {tq, tq+32, tq+64, tq+96}
    const int ng = tid >> 5;    // nodes {4ng .. 4ng+3}

    // ---- phase 2: emb = relu(W2 @ agg2) : sA -> sB
    {
        double acc[4][4] = {};
        const float* wr[4];
        const double* ar[4];
        #pragma unroll
        for (int i = 0; i < 4; i++) wr[i] = &W2[(tq + 32 * i) * 128];
        #pragma unroll
        for (int j = 0; j < 4; j++) ar[j] = &sA[(4 * ng + j) * 128];
        #pragma unroll 8
        for (int kp = 0; kp < 64; kp++) {
            float2 wv[4]; double2 av[4];
            #pragma unroll
            for (int i = 0; i < 4; i++) wv[i] = *(const float2*)&wr[i][2 * kp];
            #pragma unroll
            for (int j = 0; j < 4; j++) av[j] = *(const double2*)&ar[j][2 * kp];
            #pragma unroll
            for (int i = 0; i < 4; i++) {
                double wx = (double)wv[i].x, wy = (double)wv[i].y;
                #pragma unroll
                for (int j = 0; j < 4; j++)
                    acc[i][j] += wx * av[j].x + wy * av[j].y;
            }
        }
        #pragma unroll
        for (int i = 0; i < 4; i++)
            #pragma unroll
            for (int j = 0; j < 4; j++)
                sB[(4 * ng + j) * 128 + tq + 32 * i] = fmax(acc[i][j], 0.0);
    }
    __syncthreads();

    // ---- phase 3: xa = relu(wpad[:,:128] @ emb + wpad[:,128]*rem + b_a) : sB -> sA
    {
        double acc[4][4] = {};
        const float* wr[4];
        const double* ar[4];
        #pragma unroll
        for (int i = 0; i < 4; i++) wr[i] = &wpad[(tq + 32 * i) * WSTRIDE];
        #pragma unroll
        for (int j = 0; j < 4; j++) ar[j] = &sB[(4 * ng + j) * 128];
        #pragma unroll 8
        for (int kp = 0; kp < 64; kp++) {
            float2 wv[4]; double2 av[4];
            #pragma unroll
            for (int i = 0; i < 4; i++) wv[i] = *(const float2*)&wr[i][2 * kp];
            #pragma unroll
            for (int j = 0; j < 4; j++) av[j] = *(const double2*)&ar[j][2 * kp];
            #pragma unroll
            for (int i = 0; i < 4; i++) {
                double wx = (double)wv[i].x, wy = (double)wv[i].y;
                #pragma unroll
                for (int j = 0; j < 4; j++)
                    acc[i][j] += wx * av[j].x + wy * av[j].y;
            }
        }
        const double rem = (double)(psz[0] - npe[0]);
        #pragma unroll
        for (int i = 0; i < 4; i++) {
            int o = tq + 32 * i;
            double add = (double)wpad[o * WSTRIDE + 128] * rem + (double)b_a[o];
            #pragma unroll
            for (int j = 0; j < 4; j++)
                sA[(4 * ng + j) * 128 + o] = fmax(acc[i][j] + add, 0.0);
        }
    }
    __syncthreads();

    // ---- phase 4: xb = relu(w_b @ xa + b_b) : sA -> sB[n*64+o], o<64
    {
        double acc[2][4] = {};
        const float* wr[2];
        const double* ar[4];
        #pragma unroll
        for (int i = 0; i < 2; i++) wr[i] = &w_b[(tq + 32 * i) * 128];
        #pragma unroll
        for (int j = 0; j < 4; j++) ar[j] = &sA[(4 * ng + j) * 128];
        #pragma unroll 8
        for (int kp = 0; kp < 64; kp++) {
            float2 wv[2]; double2 av[4];
            #pragma unroll
            for (int i = 0; i < 2; i++) wv[i] = *(const float2*)&wr[i][2 * kp];
            #pragma unroll
            for (int j = 0; j < 4; j++) av[j] = *(const double2*)&ar[j][2 * kp];
            #pragma unroll
            for (int i = 0; i < 2; i++) {
                double wx = (double)wv[i].x, wy = (double)wv[i].y;
                #pragma unroll
                for (int j = 0; j < 4; j++)
                    acc[i][j] += wx * av[j].x + wy * av[j].y;
            }
        }
        #pragma unroll
        for (int i = 0; i < 2; i++) {
            int o = tq + 32 * i;
            double bb = (double)b_b[o];
            #pragma unroll
            for (int j = 0; j < 4; j++)
                sB[(4 * ng + j) * 64 + o] = fmax(acc[i][j] + bb, 0.0);
        }
    }
    __syncthreads();

    // ---- phase 5: score = w_c . xb + b_c   (8 threads per node)
    {
        const int j8 = tid & 7, ns = tid >> 3;
        double v = 0.0;
        #pragma unroll
        for (int r = 0; r < 8; r++)
            v += (double)w_c[j8 + 8 * r] * sB[ns * 64 + j8 + 8 * r];
        v += __shfl_down(v, 4);
        v += __shfl_down(v, 2);
        v += __shfl_down(v, 1);
        if (j8 == 0)
            scoresd[base + ns] = v + (double)b_c[0];
    }
}

// ---------------- softmax chain: 3 kernels ----------------
__global__ __launch_bounds__(256) void reduce_max_kernel(
    const double* __restrict__ s, double* __restrict__ pmax)
{
    __shared__ double red[4];
    const int tid = threadIdx.x;
    double m = -INFINITY;
    for (int i = blockIdx.x * 256 + tid; i < N_NODES; i += gridDim.x * 256)
        m = fmax(m, s[i]);
    #pragma unroll
    for (int off = 32; off > 0; off >>= 1) m = fmax(m, __shfl_down(m, off));
    if ((tid & 63) == 0) red[tid >> 6] = m;
    __syncthreads();
    if (tid == 0)
        pmax[blockIdx.x] = fmax(fmax(red[0], red[1]), fmax(red[2], red[3]));
}

__global__ __launch_bounds__(256) void exp_sum_kernel(
    double* __restrict__ s, const double* __restrict__ pmax,
    double* __restrict__ psum)
{
    __shared__ double red[4];
    const int tid = threadIdx.x;
    double m = pmax[tid];
    #pragma unroll
    for (int off = 32; off > 0; off >>= 1) m = fmax(m, __shfl_down(m, off));
    if ((tid & 63) == 0) red[tid >> 6] = m;
    __syncthreads();
    m = fmax(fmax(red[0], red[1]), fmax(red[2], red[3]));
    __syncthreads();

    double acc = 0.0;
    for (int i = blockIdx.x * 256 + tid; i < N_NODES; i += gridDim.x * 256) {
        double e = exp(s[i] - m);
        s[i] = e;
        acc += e;
    }
    #pragma unroll
    for (int off = 32; off > 0; off >>= 1) acc += __shfl_down(acc, off);
    if ((tid & 63) == 0) red[tid >> 6] = acc;
    __syncthreads();
    if (tid == 0)
        psum[blockIdx.x] = (red[0] + red[1]) + (red[2] + red[3]);
}

__global__ __launch_bounds__(256) void scale_kernel(
    const double* __restrict__ e, const double* __restrict__ psum,
    float* __restrict__ out)
{
    __shared__ double red[4];
    const int tid = threadIdx.x;
    double acc = psum[tid];
    #pragma unroll
    for (int off = 32; off > 0; off >>= 1) acc += __shfl_down(acc, off);
    if ((tid & 63) == 0) red[tid >> 6] = acc;
    __syncthreads();
    const double invS = 1.0 / ((red[0] + red[1]) + (red[2] + red[3]));
    const int i = blockIdx.x * 256 + tid;
    if (i < N_NODES) out[i] = (float)(e[i] * invS);
}

// ---------------- launch ----------------
extern "C" void kernel_launch(void* const* d_in, const int* in_sizes, int n_in,
                              void* d_out, int out_size, void* d_ws, size_t ws_size,
                              hipStream_t stream)
{
    const int*   nodes = (const int*)  d_in[0];
    const float* feat  = (const float*)d_in[1];
    const int*   n1    = (const int*)  d_in[2];
    const int*   n2    = (const int*)  d_in[3];
    const float* W1    = (const float*)d_in[4];
    const float* W2    = (const float*)d_in[5];
    const float* w_a   = (const float*)d_in[6];
    const float* b_a   = (const float*)d_in[7];
    const float* w_b   = (const float*)d_in[8];
    const float* b_b   = (const float*)d_in[9];
    const float* w_c   = (const float*)d_in[10];
    const float* b_c   = (const float*)d_in[11];
    const int*   psz   = (const int*)  d_in[12];
    const int*   npe   = (const int*)  d_in[13];
    float* out = (float*)d_out;

    double* agg1d   = (double*)d_ws;                       // 300000
    double* scoresd = agg1d + (size_t)N_NODES * 3;         // 100000
    double* pmax    = scoresd + N_NODES;                   // 256
    double* psum    = pmax + 256;                          // 256
    float*  wpad    = (float*)(psum + 256);                // 128*130 floats

    prep_kernel<<<25000 + 65, 256, 0, stream>>>(feat, n1, w_a, agg1d, wpad);
    enc2_mlp_kernel<<<N_NODES / NT, 128, 0, stream>>>(
        nodes, n2, agg1d, W1, W2, wpad, b_a, w_b, b_b, w_c, b_c, psz, npe, scoresd);
    reduce_max_kernel<<<256, 256, 0, stream>>>(scoresd, pmax);
    exp_sum_kernel<<<256, 256, 0, stream>>>(scoresd, pmax, psum);
    scale_kernel<<<(N_NODES + 255) / 256, 256, 0, stream>>>(scoresd, psum, out);
}